// Round 2
// baseline (391.299 us; speedup 1.0000x reference)
//
#include <hip/hip_runtime.h>
#include <math.h>

namespace {

constexpr int kB = 64, kN = 325, kT = 12, kHID = 64, kMH = 32, kMS = 20, kID = 3, kE = 3;
constexpr int kBN = kB * kN;
constexpr int kThreads = 256;
constexpr float kEps = 1e-8f;

__global__ __launch_bounds__(kThreads) void testam_fused(
    const float* __restrict__ input, const float* __restrict__ h0,
    const float* __restrict__ h1, const float* __restrict__ h2,
    const float* __restrict__ memw, const float* __restrict__ iq,
    const float* __restrict__ hq, const float* __restrict__ kw,
    const float* __restrict__ vw, float* __restrict__ out)
{
  const int bn = blockIdx.x;
  const int tid = threadIdx.x;

  __shared__ float sh_h[kE][kT][kHID];       // 9216 B   staged hidden tiles
  __shared__ float sh_QKV[3][kE][kT][kMH];   // 13824 B  Q,K,V (Q slot reused for att@V)
  __shared__ float sh_mem[kT][kMH];          // memories
  __shared__ float sh_eng[kE][kT][kT];       // energy / attn
  __shared__ float sh_memw[kMS][kMH];
  __shared__ float sh_iq[kID][kMH];
  __shared__ float sh_in[kT][kID];
  __shared__ float sh_qv[kT][kMH];
  __shared__ float sh_sc[kT][kMS];

  // ---- stage inputs ----
  {
    const size_t hb = (size_t)bn * kT * kHID;
    float* dsth = &sh_h[0][0][0];
    for (int i = tid; i < kE * kT * kHID; i += kThreads) {
      int e = i / (kT * kHID);
      int r = i - e * (kT * kHID);
      const float* hp = (e == 0) ? h0 : (e == 1) ? h1 : h2;
      dsth[i] = hp[hb + r];
    }
    for (int i = tid; i < kMS * kMH; i += kThreads) (&sh_memw[0][0])[i] = memw[i];
    if (tid < kID * kMH) (&sh_iq[0][0])[tid] = iq[tid];
    if (tid < kT * kID) (&sh_in[0][0])[tid] = input[(size_t)bn * kT * kID + tid];
  }
  __syncthreads();

  // ---- q = input @ input_query  (12x32 entries, 3-dots) ----
  for (int i = tid; i < kT * kMH; i += kThreads) {
    int t = i >> 5, m = i & 31;
    float acc = 0.f;
    #pragma unroll
    for (int d = 0; d < kID; ++d) acc += sh_in[t][d] * sh_iq[d][m];
    sh_qv[t][m] = acc;
  }
  __syncthreads();

  // ---- mem scores = q @ memory^T  (12x20 entries, 32-dots) ----
  for (int i = tid; i < kT * kMS; i += kThreads) {
    int t = i / kMS, s = i - t * kMS;
    float acc = 0.f;
    #pragma unroll
    for (int m = 0; m < kMH; ++m) acc += sh_qv[t][m] * sh_memw[s][m];
    sh_sc[t][s] = acc;
  }
  __syncthreads();

  // softmax over s per t (12 rows of 20)
  if (tid < kT) {
    int t = tid;
    float mx = sh_sc[t][0];
    for (int s = 1; s < kMS; ++s) mx = fmaxf(mx, sh_sc[t][s]);
    float sum = 0.f;
    for (int s = 0; s < kMS; ++s) { float e2 = __expf(sh_sc[t][s] - mx); sh_sc[t][s] = e2; sum += e2; }
    float inv = 1.f / sum;
    for (int s = 0; s < kMS; ++s) sh_sc[t][s] *= inv;
  }
  __syncthreads();

  // ---- memories = score @ memory  (12x32 entries, 20-dots) ----
  for (int i = tid; i < kT * kMH; i += kThreads) {
    int t = i >> 5, m = i & 31;
    float acc = 0.f;
    #pragma unroll
    for (int s = 0; s < kMS; ++s) acc += sh_sc[t][s] * sh_memw[s][m];
    sh_mem[t][m] = acc;
  }
  __syncthreads();

  // ---- Q,K,V projections: 3 mats x 3 experts x 32 cols = 288 tasks ----
  // Each task computes one output column for all 12 t's -> each weight element
  // read exactly once per block (streamed through L2).
  for (int task = tid; task < 3 * kE * kMH; task += kThreads) {
    int mat = task / (kE * kMH);
    int em = task - mat * (kE * kMH);
    int e = em >> 5, m = em & 31;
    const float* __restrict__ W =
        ((mat == 0) ? hq : (mat == 1) ? kw : vw) + e * (kHID * kMH) + m;
    float acc[kT];
    #pragma unroll
    for (int t = 0; t < kT; ++t) acc[t] = 0.f;
    for (int k = 0; k < kHID; ++k) {
      float w = W[k * kMH];
      #pragma unroll
      for (int t = 0; t < kT; ++t) acc[t] += sh_h[e][t][k] * w;
    }
    #pragma unroll
    for (int t = 0; t < kT; ++t) sh_QKV[mat][e][t][m] = acc[t];
  }
  __syncthreads();

  // ---- energy = Q @ K^T  (3x12x12 entries, 32-dots) ----
  for (int i = tid; i < kE * kT * kT; i += kThreads) {
    int e = i / (kT * kT);
    int r = i - e * (kT * kT);
    int t = r / kT, s = r - t * kT;
    float acc = 0.f;
    #pragma unroll
    for (int m = 0; m < kMH; ++m) acc += sh_QKV[0][e][t][m] * sh_QKV[1][e][s][m];
    sh_eng[e][t][s] = acc;
  }
  __syncthreads();

  // softmax over s per (e,t): 36 rows of 12
  if (tid < kE * kT) {
    int e = tid / kT, t = tid - e * kT;
    float mx = sh_eng[e][t][0];
    for (int s = 1; s < kT; ++s) mx = fmaxf(mx, sh_eng[e][t][s]);
    float sum = 0.f;
    for (int s = 0; s < kT; ++s) { float e2 = __expf(sh_eng[e][t][s] - mx); sh_eng[e][t][s] = e2; sum += e2; }
    float inv = 1.f / sum;
    for (int s = 0; s < kT; ++s) sh_eng[e][t][s] *= inv;
  }
  __syncthreads();

  // ---- hidden_att = attn @ V  (3x12x32 entries, 12-dots) -> reuse Q slot ----
  for (int i = tid; i < kE * kT * kMH; i += kThreads) {
    int e = i / (kT * kMH);
    int r = i - e * (kT * kMH);
    int t = r >> 5, m = r & 31;
    float acc = 0.f;
    #pragma unroll
    for (int s = 0; s < kT; ++s) acc += sh_eng[e][t][s] * sh_QKV[2][e][s][m];
    sh_QKV[0][e][t][m] = acc;
  }
  __syncthreads();

  // ---- cosine similarity + output (36 rows) ----
  if (tid < kE * kT) {
    int e = tid / kT, t = tid - e * kT;
    float dot = 0.f, na = 0.f, nb = 0.f;
    #pragma unroll
    for (int m = 0; m < kMH; ++m) {
      float a = sh_mem[t][m], bv = sh_QKV[0][e][t][m];
      dot += a * bv; na += a * a; nb += bv * bv;
    }
    float denom = fmaxf(sqrtf(na) * sqrtf(nb), kEps);
    out[((size_t)bn * kT + t) * kE + e] = dot / denom;
  }
}

}  // namespace

extern "C" void kernel_launch(void* const* d_in, const int* in_sizes, int n_in,
                              void* d_out, int out_size, void* d_ws, size_t ws_size,
                              hipStream_t stream) {
  const float* input = (const float*)d_in[0];
  const float* h0    = (const float*)d_in[1];
  const float* h1    = (const float*)d_in[2];
  const float* h2    = (const float*)d_in[3];
  const float* memw  = (const float*)d_in[4];
  const float* iq    = (const float*)d_in[5];
  const float* hq    = (const float*)d_in[6];
  const float* kw    = (const float*)d_in[7];
  const float* vw    = (const float*)d_in[8];
  float* out = (float*)d_out;

  testam_fused<<<kBN, kThreads, 0, stream>>>(input, h0, h1, h2, memw, iq, hq, kw, vw, out);
}

// Round 3
// 286.883 us; speedup vs baseline: 1.3640x; 1.3640x over previous
//
#include <hip/hip_runtime.h>
#include <math.h>

typedef __attribute__((ext_vector_type(8))) short short8;
typedef __attribute__((ext_vector_type(4))) float f32x4;

namespace {

constexpr int kT = 12, kMS = 20, kE = 3;
constexpr int kSites = 64 * 325;                        // 20800
constexpr int kWaves = 6;
constexpr int kThreads = kWaves * 64;                   // 384
constexpr int kBlocksPerE = (kSites + kWaves - 1) / kWaves;  // 3467

// split x into hi (truncated bf16) and lo (bf16 of remainder): x ~= hi + lo, err ~2^-16|x|
__device__ __forceinline__ void split1(float x, unsigned& hi, unsigned& lo) {
  unsigned u = __float_as_uint(x);
  hi = u >> 16;
  float r = x - __uint_as_float(u & 0xFFFF0000u);   // exact (Sterbenz)
  lo = __float_as_uint(r) >> 16;
}

__device__ __forceinline__ unsigned short bf_rtn(float x) {  // round-nearest-even bf16
  unsigned u = __float_as_uint(x);
  return (unsigned short)((u + 0x7FFFu + ((u >> 16) & 1u)) >> 16);
}

#define MFMA32(a, b, c) __builtin_amdgcn_mfma_f32_16x16x32_bf16((a), (b), (c), 0, 0, 0)
#define LDS_FENCE() asm volatile("s_waitcnt lgkmcnt(0)" ::: "memory")

// Fragment conventions (16x16x32 bf16):
//   A: lane l holds A[row = l&15][k = (l>>4)*8 + j], j=0..7
//   B: lane l holds B[k = (l>>4)*8 + j][col = l&15]
//   C/D: lane l holds D[row = (l>>4)*4 + reg][col = l&15]   (m89-verified)
__global__ __launch_bounds__(kThreads, 3) void testam_mfma(
    const float* __restrict__ input, const float* __restrict__ h0,
    const float* __restrict__ h1, const float* __restrict__ h2,
    const float* __restrict__ memw, const float* __restrict__ iq,
    const float* __restrict__ hq, const float* __restrict__ kwt,
    const float* __restrict__ vw, float* __restrict__ out) {

  __shared__ __align__(16) unsigned short wlds[2][12][512];  // [half][mat*4+k0i*2+n0i][l*8+j]
  __shared__ __align__(16) unsigned short mwT[2][2][512];    // scores-B: memw^T frags
  __shared__ __align__(16) unsigned short mwB[2][2][512];    // memories-B: memw frags
  __shared__ __align__(16) unsigned bufQ[kWaves][16 * 33];   // Q split-packed; later attn planes
  __shared__ __align__(16) unsigned bufK[kWaves][16 * 33];   // K split-packed; later mem-attnw
  __shared__ __align__(16) unsigned short vT[kWaves][32 * 16];  // V^T single bf16

  const int tid = threadIdx.x;
  const int e = blockIdx.x / kBlocksPerE;
  const int l = tid & 63, wv = tid >> 6;
  const int g = l >> 4, c = l & 15;
  const int site = (blockIdx.x % kBlocksPerE) * kWaves + wv;

  // ---- block staging: expert-e weight fragments (hi/lo) ----
  for (int idx = tid; idx < 768; idx += kThreads) {
    int ll = idx & 63, fi = idx >> 6;
    int mat = fi >> 2, k0i = (fi >> 1) & 1, n0i = fi & 1;
    int gg = ll >> 4, cc = ll & 15;
    const float* wp = ((mat == 0) ? hq : (mat == 1) ? kwt : vw) + e * 2048
                      + (k0i * 32 + gg * 8) * 32 + n0i * 16 + cc;
    short8 sh, sl;
    #pragma unroll
    for (int j = 0; j < 8; ++j) {
      unsigned h, lo; split1(wp[j * 32], h, lo);
      sh[j] = (short)h; sl[j] = (short)lo;
    }
    *(short8*)&wlds[0][fi][ll * 8] = sh;
    *(short8*)&wlds[1][fi][ll * 8] = sl;
  }
  // scores-B frags: B[k=m][col=s] = memw[s][m]
  for (int idx = tid; idx < 128; idx += kThreads) {
    int ll = idx & 63, n0i = idx >> 6;
    int gg = ll >> 4, cc = ll & 15, s = n0i * 16 + cc;
    short8 sh, sl;
    #pragma unroll
    for (int j = 0; j < 8; ++j) {
      float v = (s < kMS) ? memw[s * 32 + gg * 8 + j] : 0.f;
      unsigned h, lo; split1(v, h, lo);
      sh[j] = (short)h; sl[j] = (short)lo;
    }
    *(short8*)&mwT[0][n0i][ll * 8] = sh;
    *(short8*)&mwT[1][n0i][ll * 8] = sl;
  }
  // memories-B frags: B[k=s][col=m] = memw[s][m], zero-padded s>=20
  for (int idx = tid; idx < 128; idx += kThreads) {
    int ll = idx & 63, n0i = idx >> 6;
    int gg = ll >> 4, cc = ll & 15;
    short8 sh, sl;
    #pragma unroll
    for (int j = 0; j < 8; ++j) {
      int k = gg * 8 + j;
      float v = (k < kMS) ? memw[k * 32 + n0i * 16 + cc] : 0.f;
      unsigned h, lo; split1(v, h, lo);
      sh[j] = (short)h; sl[j] = (short)lo;
    }
    *(short8*)&mwB[0][n0i][ll * 8] = sh;
    *(short8*)&mwB[1][n0i][ll * 8] = sl;
  }
  __syncthreads();

  if (site >= kSites) return;

  const float* hsrc = ((e == 0) ? h0 : (e == 1) ? h1 : h2) + (size_t)site * (kT * 64);

  // ---- A-fragments of h (rows 12..15 zero) ----
  short8 ah[2], al[2];
  #pragma unroll
  for (int k0i = 0; k0i < 2; ++k0i) {
    short8 sh, sl;
    if (c < kT) {
      const float* p = hsrc + c * 64 + k0i * 32 + g * 8;
      #pragma unroll
      for (int j = 0; j < 8; ++j) {
        unsigned h, lo; split1(p[j], h, lo);
        sh[j] = (short)h; sl[j] = (short)lo;
      }
    } else {
      #pragma unroll
      for (int j = 0; j < 8; ++j) { sh[j] = 0; sl[j] = 0; }
    }
    ah[k0i] = sh; al[k0i] = sl;
  }

  const f32x4 fz = {0.f, 0.f, 0.f, 0.f};

  // ---- Q,K,V projections (3-term bf16x3) ----
  #pragma unroll
  for (int mat = 0; mat < 3; ++mat) {
    f32x4 acc[2] = {fz, fz};
    #pragma unroll
    for (int n0i = 0; n0i < 2; ++n0i) {
      #pragma unroll
      for (int k0i = 0; k0i < 2; ++k0i) {
        int fi = mat * 4 + k0i * 2 + n0i;
        short8 bh = *(const short8*)&wlds[0][fi][l * 8];
        short8 bl = *(const short8*)&wlds[1][fi][l * 8];
        acc[n0i] = MFMA32(ah[k0i], bh, acc[n0i]);
        acc[n0i] = MFMA32(ah[k0i], bl, acc[n0i]);
        acc[n0i] = MFMA32(al[k0i], bh, acc[n0i]);
      }
    }
    if (mat < 2) {  // Q,K: split-packed u32 scratch [row t][col m], stride 33
      unsigned* dst = (mat == 0) ? bufQ[wv] : bufK[wv];
      #pragma unroll
      for (int n0i = 0; n0i < 2; ++n0i)
        #pragma unroll
        for (int r = 0; r < 4; ++r) {
          unsigned h, lo; split1(acc[n0i][r], h, lo);
          dst[(g * 4 + r) * 33 + n0i * 16 + c] = h | (lo << 16);
        }
    } else {  // V: transposed single-bf16  vT[m][s=t]
      #pragma unroll
      for (int n0i = 0; n0i < 2; ++n0i)
        #pragma unroll
        for (int r = 0; r < 4; ++r)
          vT[wv][(n0i * 16 + c) * 16 + g * 4 + r] = bf_rtn(acc[n0i][r]);
    }
  }
  LDS_FENCE();

  // ---- energy = Q K^T (one 16x16 tile, 3-term) ----
  short8 qh, ql, kh, kl;
  #pragma unroll
  for (int j = 0; j < 8; ++j) {
    unsigned uq = bufQ[wv][c * 33 + g * 8 + j];
    unsigned uk = bufK[wv][c * 33 + g * 8 + j];
    qh[j] = (short)(uq & 0xFFFFu); ql[j] = (short)(uq >> 16);
    kh[j] = (short)(uk & 0xFFFFu); kl[j] = (short)(uk >> 16);
  }
  f32x4 eng = fz;
  eng = MFMA32(qh, kh, eng);
  eng = MFMA32(qh, kl, eng);
  eng = MFMA32(ql, kh, eng);

  // ---- softmax over s (cols, 16-lane shuffle reduce); store attn hi/lo planes in bufQ ----
  unsigned short* attnHi = (unsigned short*)&bufQ[wv][0];
  unsigned short* attnLo = attnHi + 256;
  #pragma unroll
  for (int r = 0; r < 4; ++r) {
    float v = (c < kT) ? eng[r] : -1e30f;
    float mx = v;
    #pragma unroll
    for (int m = 1; m < 16; m <<= 1) mx = fmaxf(mx, __shfl_xor(mx, m));
    float ev = (c < kT) ? __expf(eng[r] - mx) : 0.f;
    float sm = ev;
    #pragma unroll
    for (int m = 1; m < 16; m <<= 1) sm += __shfl_xor(sm, m);
    float wgt = ev / sm;
    unsigned h, lo; split1(wgt, h, lo);
    attnHi[(g * 4 + r) * 16 + c] = (unsigned short)h;
    attnLo[(g * 4 + r) * 16 + c] = (unsigned short)lo;
  }
  LDS_FENCE();

  // ---- hidden_att = attn @ V  (K=32, s>=16 lanes carry zero A) ----
  short8 ah2, al2;
  if (g < 2) {
    ah2 = *(const short8*)&attnHi[c * 16 + g * 8];
    al2 = *(const short8*)&attnLo[c * 16 + g * 8];
  } else {
    #pragma unroll
    for (int j = 0; j < 8; ++j) { ah2[j] = 0; al2[j] = 0; }
  }
  f32x4 ha[2];
  #pragma unroll
  for (int n0i = 0; n0i < 2; ++n0i) {
    short8 bv = *(const short8*)&vT[wv][(n0i * 16 + c) * 16 + (g & 1) * 8];
    ha[n0i] = MFMA32(ah2, bv, fz);
    ha[n0i] = MFMA32(al2, bv, ha[n0i]);
  }

  // ---- memory path: q = input@iq (VALU, in A-frag layout) ----
  float in0 = 0.f, in1 = 0.f, in2 = 0.f;
  if (c < kT) {
    const float* ip = input + (size_t)site * (kT * 3) + c * 3;
    in0 = ip[0]; in1 = ip[1]; in2 = ip[2];
  }
  short8 qmh, qml;
  #pragma unroll
  for (int j = 0; j < 8; ++j) {
    int m = g * 8 + j;
    float qv = in0 * iq[m] + in1 * iq[32 + m] + in2 * iq[64 + m];
    unsigned h, lo; split1(qv, h, lo);
    qmh[j] = (short)h; qml[j] = (short)lo;
  }
  // mem scores = q @ memw^T  (N=20 over two tiles, 3-term)
  f32x4 sc[2];
  #pragma unroll
  for (int n0i = 0; n0i < 2; ++n0i) {
    short8 bh = *(const short8*)&mwT[0][n0i][l * 8];
    short8 bl = *(const short8*)&mwT[1][n0i][l * 8];
    sc[n0i] = MFMA32(qmh, bh, fz);
    sc[n0i] = MFMA32(qmh, bl, sc[n0i]);
    sc[n0i] = MFMA32(qml, bh, sc[n0i]);
  }
  // softmax over s=0..19 (both tiles)
  float w0[4], w1[4];
  #pragma unroll
  for (int r = 0; r < 4; ++r) {
    float v0 = sc[0][r];
    float v1 = (c < 4) ? sc[1][r] : -1e30f;
    float mx = fmaxf(v0, v1);
    #pragma unroll
    for (int m = 1; m < 16; m <<= 1) mx = fmaxf(mx, __shfl_xor(mx, m));
    float e0 = __expf(v0 - mx);
    float e1 = (c < 4) ? __expf(sc[1][r] - mx) : 0.f;
    float sm = e0 + e1;
    #pragma unroll
    for (int m = 1; m < 16; m <<= 1) sm += __shfl_xor(sm, m);
    float inv = 1.f / sm;
    w0[r] = e0 * inv; w1[r] = e1 * inv;
  }
  // re-layout mem-attn weights to A-frag via bufK (K dead), cols 20..31 zeroed
  #pragma unroll
  for (int r = 0; r < 4; ++r) {
    int t = g * 4 + r;
    unsigned h, lo; split1(w0[r], h, lo);
    bufK[wv][t * 33 + c] = h | (lo << 16);
    unsigned pv = 0u;
    if (c < 4) { split1(w1[r], h, lo); pv = h | (lo << 16); }
    bufK[wv][t * 33 + 16 + c] = pv;
  }
  LDS_FENCE();
  short8 awh, awl;
  #pragma unroll
  for (int j = 0; j < 8; ++j) {
    unsigned u = bufK[wv][c * 33 + g * 8 + j];
    awh[j] = (short)(u & 0xFFFFu); awl[j] = (short)(u >> 16);
  }
  // memories = attnw @ memw  (3-term) -> same C layout as ha
  f32x4 mem[2];
  #pragma unroll
  for (int n0i = 0; n0i < 2; ++n0i) {
    short8 bh = *(const short8*)&mwB[0][n0i][l * 8];
    short8 bl = *(const short8*)&mwB[1][n0i][l * 8];
    mem[n0i] = MFMA32(awh, bh, fz);
    mem[n0i] = MFMA32(awh, bl, mem[n0i]);
    mem[n0i] = MFMA32(awl, bh, mem[n0i]);
  }

  // ---- cosine similarity + store ----
  #pragma unroll
  for (int r = 0; r < 4; ++r) {
    float dot = mem[0][r] * ha[0][r] + mem[1][r] * ha[1][r];
    float na  = mem[0][r] * mem[0][r] + mem[1][r] * mem[1][r];
    float nb  = ha[0][r] * ha[0][r] + ha[1][r] * ha[1][r];
    #pragma unroll
    for (int m = 1; m < 16; m <<= 1) {
      dot += __shfl_xor(dot, m);
      na  += __shfl_xor(na, m);
      nb  += __shfl_xor(nb, m);
    }
    int t = g * 4 + r;
    if (c == 0 && t < kT) {
      float cv = dot / fmaxf(sqrtf(na) * sqrtf(nb), 1e-8f);
      out[(size_t)site * (kT * kE) + t * kE + e] = cv;
    }
  }
}

}  // namespace

extern "C" void kernel_launch(void* const* d_in, const int* in_sizes, int n_in,
                              void* d_out, int out_size, void* d_ws, size_t ws_size,
                              hipStream_t stream) {
  const float* input = (const float*)d_in[0];
  const float* h0    = (const float*)d_in[1];
  const float* h1    = (const float*)d_in[2];
  const float* h2    = (const float*)d_in[3];
  const float* memw  = (const float*)d_in[4];
  const float* iq    = (const float*)d_in[5];
  const float* hq    = (const float*)d_in[6];
  const float* kw    = (const float*)d_in[7];
  const float* vw    = (const float*)d_in[8];
  float* out = (float*)d_out;

  testam_mfma<<<kE * kBlocksPerE, kThreads, 0, stream>>>(
      input, h0, h1, h2, memw, iq, hq, kw, vw, out);
}

// Round 4
// 217.682 us; speedup vs baseline: 1.7976x; 1.3179x over previous
//
#include <hip/hip_runtime.h>
#include <math.h>

typedef __attribute__((ext_vector_type(8))) short short8;
typedef __attribute__((ext_vector_type(4))) float f32x4;

namespace {

constexpr int kT = 12, kMS = 20, kE = 3;
constexpr int kSites = 64 * 325;                 // 20800
constexpr int kWaves = 6;
constexpr int kThreads = kWaves * 64;            // 384
constexpr int kNB = 170;                         // blocks per expert (510 total ~= 2/CU)
constexpr int kStride = kNB * kWaves;            // 1020 sites per sweep
constexpr int kIters = (kSites + kStride - 1) / kStride;  // 21

// split x into hi (truncated bf16) and lo (bf16 of remainder): x ~= hi + lo
__device__ __forceinline__ void split1(float x, unsigned& hi, unsigned& lo) {
  unsigned u = __float_as_uint(x);
  hi = u >> 16;
  float r = x - __uint_as_float(u & 0xFFFF0000u);   // exact (Sterbenz)
  lo = __float_as_uint(r) >> 16;
}

__device__ __forceinline__ unsigned short bf_rtn(float x) {  // round-nearest-even bf16
  unsigned u = __float_as_uint(x);
  return (unsigned short)((u + 0x7FFFu + ((u >> 16) & 1u)) >> 16);
}

#define MFMA32(a, b, c) __builtin_amdgcn_mfma_f32_16x16x32_bf16((a), (b), (c), 0, 0, 0)
#define LDS_FENCE() asm volatile("s_waitcnt lgkmcnt(0)" ::: "memory")

// Fragment conventions (16x16x32 bf16):
//   A: lane l holds A[row = l&15][k = (l>>4)*8 + j]
//   B: lane l holds B[k = (l>>4)*8 + j][col = l&15]
//   C/D: lane l holds D[row = (l>>4)*4 + reg][col = l&15]   (m89-verified)
__global__ __launch_bounds__(kThreads, 3) void testam_mfma(
    const float* __restrict__ input, const float* __restrict__ h0,
    const float* __restrict__ h1, const float* __restrict__ h2,
    const float* __restrict__ memw, const float* __restrict__ iq,
    const float* __restrict__ hq, const float* __restrict__ kwt,
    const float* __restrict__ vw, float* __restrict__ out) {

  __shared__ __align__(16) unsigned short wlds[2][12][512];  // weight frags (hi/lo)
  __shared__ __align__(16) unsigned short mwT[2][2][512];    // scores-B: memw^T frags
  __shared__ __align__(16) unsigned short mwB[2][2][512];    // memories-B: memw frags
  __shared__ __align__(16) unsigned bufQ[kWaves][16 * 33];   // Q split-packed; later attn planes
  __shared__ __align__(16) unsigned bufK[kWaves][16 * 33];   // K split-packed; later mem-attnw
  __shared__ __align__(16) unsigned short vT[kWaves][32 * 16];  // V^T single bf16

  const int tid = threadIdx.x;
  const int e = blockIdx.x / kNB;
  const int b = blockIdx.x % kNB;
  const int l = tid & 63, wv = tid >> 6;
  const int g = l >> 4, c = l & 15;

  // ---- one-time staging: expert-e weight fragments (hi/lo) ----
  for (int idx = tid; idx < 768; idx += kThreads) {
    int ll = idx & 63, fi = idx >> 6;
    int mat = fi >> 2, k0i = (fi >> 1) & 1, n0i = fi & 1;
    int gg = ll >> 4, cc = ll & 15;
    const float* wp = ((mat == 0) ? hq : (mat == 1) ? kwt : vw) + e * 2048
                      + (k0i * 32 + gg * 8) * 32 + n0i * 16 + cc;
    short8 sh, sl;
    #pragma unroll
    for (int j = 0; j < 8; ++j) {
      unsigned h, lo; split1(wp[j * 32], h, lo);
      sh[j] = (short)h; sl[j] = (short)lo;
    }
    *(short8*)&wlds[0][fi][ll * 8] = sh;
    *(short8*)&wlds[1][fi][ll * 8] = sl;
  }
  for (int idx = tid; idx < 128; idx += kThreads) {  // B[k=m][col=s] = memw[s][m]
    int ll = idx & 63, n0i = idx >> 6;
    int gg = ll >> 4, cc = ll & 15, s = n0i * 16 + cc;
    short8 sh, sl;
    #pragma unroll
    for (int j = 0; j < 8; ++j) {
      float v = (s < kMS) ? memw[s * 32 + gg * 8 + j] : 0.f;
      unsigned h, lo; split1(v, h, lo);
      sh[j] = (short)h; sl[j] = (short)lo;
    }
    *(short8*)&mwT[0][n0i][ll * 8] = sh;
    *(short8*)&mwT[1][n0i][ll * 8] = sl;
  }
  for (int idx = tid; idx < 128; idx += kThreads) {  // B[k=s][col=m] = memw[s][m]
    int ll = idx & 63, n0i = idx >> 6;
    int gg = ll >> 4, cc = ll & 15;
    short8 sh, sl;
    #pragma unroll
    for (int j = 0; j < 8; ++j) {
      int k = gg * 8 + j;
      float v = (k < kMS) ? memw[k * 32 + n0i * 16 + cc] : 0.f;
      unsigned h, lo; split1(v, h, lo);
      sh[j] = (short)h; sl[j] = (short)lo;
    }
    *(short8*)&mwB[0][n0i][ll * 8] = sh;
    *(short8*)&mwB[1][n0i][ll * 8] = sl;
  }
  __syncthreads();

  const float* hbase = (e == 0) ? h0 : (e == 1) ? h1 : h2;

  // hoist input_query columns for this lane's m-range into registers
  float iqr0[8], iqr1[8], iqr2[8];
  #pragma unroll
  for (int j = 0; j < 8; ++j) {
    int m = g * 8 + j;
    iqr0[j] = iq[m]; iqr1[j] = iq[32 + m]; iqr2[j] = iq[64 + m];
  }

  const f32x4 fz = {0.f, 0.f, 0.f, 0.f};

  // ---- site sweep with register prefetch of next site's h + input ----
  float hcur[16], hnxt[16];
  float pcur[3], pnxt[3];

  auto load_site = [&](int s, float* hr, float* pr) {
    if (s < kSites && c < kT) {
      const float* p = hbase + (size_t)s * 768 + c * 64 + g * 8;
      #pragma unroll
      for (int k0i = 0; k0i < 2; ++k0i)
        #pragma unroll
        for (int j = 0; j < 8; ++j) hr[k0i * 8 + j] = p[k0i * 32 + j];
      const float* ip = input + (size_t)s * 36 + c * 3;
      pr[0] = ip[0]; pr[1] = ip[1]; pr[2] = ip[2];
    } else {
      #pragma unroll
      for (int j = 0; j < 16; ++j) hr[j] = 0.f;
      pr[0] = pr[1] = pr[2] = 0.f;
    }
  };

  int site = b * kWaves + wv;
  load_site(site, hcur, pcur);

  for (int it = 0; it < kIters; ++it) {
    const int nsite = site + kStride;
    load_site(nsite, hnxt, pnxt);   // issue loads; consumed after body

    if (site < kSites) {
      // ---- A-fragments of h ----
      short8 ah[2], al[2];
      #pragma unroll
      for (int k0i = 0; k0i < 2; ++k0i) {
        short8 sh, sl;
        #pragma unroll
        for (int j = 0; j < 8; ++j) {
          unsigned h, lo; split1(hcur[k0i * 8 + j], h, lo);
          sh[j] = (short)h; sl[j] = (short)lo;
        }
        ah[k0i] = sh; al[k0i] = sl;
      }

      // ---- Q,K,V projections (3-term bf16x3) ----
      #pragma unroll
      for (int mat = 0; mat < 3; ++mat) {
        f32x4 acc[2] = {fz, fz};
        #pragma unroll
        for (int n0i = 0; n0i < 2; ++n0i) {
          #pragma unroll
          for (int k0i = 0; k0i < 2; ++k0i) {
            int fi = mat * 4 + k0i * 2 + n0i;
            short8 bh = *(const short8*)&wlds[0][fi][l * 8];
            short8 bl = *(const short8*)&wlds[1][fi][l * 8];
            acc[n0i] = MFMA32(ah[k0i], bh, acc[n0i]);
            acc[n0i] = MFMA32(ah[k0i], bl, acc[n0i]);
            acc[n0i] = MFMA32(al[k0i], bh, acc[n0i]);
          }
        }
        if (mat < 2) {
          unsigned* dst = (mat == 0) ? bufQ[wv] : bufK[wv];
          #pragma unroll
          for (int n0i = 0; n0i < 2; ++n0i)
            #pragma unroll
            for (int r = 0; r < 4; ++r) {
              unsigned h, lo; split1(acc[n0i][r], h, lo);
              dst[(g * 4 + r) * 33 + n0i * 16 + c] = h | (lo << 16);
            }
        } else {
          #pragma unroll
          for (int n0i = 0; n0i < 2; ++n0i)
            #pragma unroll
            for (int r = 0; r < 4; ++r)
              vT[wv][(n0i * 16 + c) * 16 + g * 4 + r] = bf_rtn(acc[n0i][r]);
        }
      }
      LDS_FENCE();

      // ---- energy = Q K^T ----
      short8 qh, ql, kh, kl;
      #pragma unroll
      for (int j = 0; j < 8; ++j) {
        unsigned uq = bufQ[wv][c * 33 + g * 8 + j];
        unsigned uk = bufK[wv][c * 33 + g * 8 + j];
        qh[j] = (short)(uq & 0xFFFFu); ql[j] = (short)(uq >> 16);
        kh[j] = (short)(uk & 0xFFFFu); kl[j] = (short)(uk >> 16);
      }
      f32x4 eng = fz;
      eng = MFMA32(qh, kh, eng);
      eng = MFMA32(qh, kl, eng);
      eng = MFMA32(ql, kh, eng);

      // ---- softmax over s; attn hi/lo planes into bufQ ----
      unsigned short* attnHi = (unsigned short*)&bufQ[wv][0];
      unsigned short* attnLo = attnHi + 256;
      #pragma unroll
      for (int r = 0; r < 4; ++r) {
        float v = (c < kT) ? eng[r] : -1e30f;
        float mx = v;
        #pragma unroll
        for (int m = 1; m < 16; m <<= 1) mx = fmaxf(mx, __shfl_xor(mx, m));
        float ev = (c < kT) ? __expf(eng[r] - mx) : 0.f;
        float sm = ev;
        #pragma unroll
        for (int m = 1; m < 16; m <<= 1) sm += __shfl_xor(sm, m);
        float wgt = ev / sm;
        unsigned h, lo; split1(wgt, h, lo);
        attnHi[(g * 4 + r) * 16 + c] = (unsigned short)h;
        attnLo[(g * 4 + r) * 16 + c] = (unsigned short)lo;
      }
      LDS_FENCE();

      // ---- hidden_att = attn @ V ----
      short8 ah2, al2;
      if (g < 2) {
        ah2 = *(const short8*)&attnHi[c * 16 + g * 8];
        al2 = *(const short8*)&attnLo[c * 16 + g * 8];
      } else {
        #pragma unroll
        for (int j = 0; j < 8; ++j) { ah2[j] = 0; al2[j] = 0; }
      }
      f32x4 ha[2];
      #pragma unroll
      for (int n0i = 0; n0i < 2; ++n0i) {
        short8 bv = *(const short8*)&vT[wv][(n0i * 16 + c) * 16 + (g & 1) * 8];
        ha[n0i] = MFMA32(ah2, bv, fz);
        ha[n0i] = MFMA32(al2, bv, ha[n0i]);
      }

      // ---- memory path: q = input@iq (VALU, A-frag layout) ----
      short8 qmh, qml;
      #pragma unroll
      for (int j = 0; j < 8; ++j) {
        float qv = pcur[0] * iqr0[j] + pcur[1] * iqr1[j] + pcur[2] * iqr2[j];
        unsigned h, lo; split1(qv, h, lo);
        qmh[j] = (short)h; qml[j] = (short)lo;
      }
      f32x4 sc[2];
      #pragma unroll
      for (int n0i = 0; n0i < 2; ++n0i) {
        short8 bh = *(const short8*)&mwT[0][n0i][l * 8];
        short8 bl = *(const short8*)&mwT[1][n0i][l * 8];
        sc[n0i] = MFMA32(qmh, bh, fz);
        sc[n0i] = MFMA32(qmh, bl, sc[n0i]);
        sc[n0i] = MFMA32(qml, bh, sc[n0i]);
      }
      float w0[4], w1[4];
      #pragma unroll
      for (int r = 0; r < 4; ++r) {
        float v0 = sc[0][r];
        float v1 = (c < 4) ? sc[1][r] : -1e30f;
        float mx = fmaxf(v0, v1);
        #pragma unroll
        for (int m = 1; m < 16; m <<= 1) mx = fmaxf(mx, __shfl_xor(mx, m));
        float e0 = __expf(v0 - mx);
        float e1 = (c < 4) ? __expf(sc[1][r] - mx) : 0.f;
        float sm = e0 + e1;
        #pragma unroll
        for (int m = 1; m < 16; m <<= 1) sm += __shfl_xor(sm, m);
        float inv = 1.f / sm;
        w0[r] = e0 * inv; w1[r] = e1 * inv;
      }
      #pragma unroll
      for (int r = 0; r < 4; ++r) {
        int t = g * 4 + r;
        unsigned h, lo; split1(w0[r], h, lo);
        bufK[wv][t * 33 + c] = h | (lo << 16);
        unsigned pv = 0u;
        if (c < 4) { split1(w1[r], h, lo); pv = h | (lo << 16); }
        bufK[wv][t * 33 + 16 + c] = pv;
      }
      LDS_FENCE();
      short8 awh, awl;
      #pragma unroll
      for (int j = 0; j < 8; ++j) {
        unsigned u = bufK[wv][c * 33 + g * 8 + j];
        awh[j] = (short)(u & 0xFFFFu); awl[j] = (short)(u >> 16);
      }
      f32x4 mem[2];
      #pragma unroll
      for (int n0i = 0; n0i < 2; ++n0i) {
        short8 bh = *(const short8*)&mwB[0][n0i][l * 8];
        short8 bl = *(const short8*)&mwB[1][n0i][l * 8];
        mem[n0i] = MFMA32(awh, bh, fz);
        mem[n0i] = MFMA32(awh, bl, mem[n0i]);
        mem[n0i] = MFMA32(awl, bh, mem[n0i]);
      }

      // ---- cosine similarity + store ----
      #pragma unroll
      for (int r = 0; r < 4; ++r) {
        float dot = mem[0][r] * ha[0][r] + mem[1][r] * ha[1][r];
        float na  = mem[0][r] * mem[0][r] + mem[1][r] * mem[1][r];
        float nb  = ha[0][r] * ha[0][r] + ha[1][r] * ha[1][r];
        #pragma unroll
        for (int m = 1; m < 16; m <<= 1) {
          dot += __shfl_xor(dot, m);
          na  += __shfl_xor(na, m);
          nb  += __shfl_xor(nb, m);
        }
        int t = g * 4 + r;
        if (c == 0 && t < kT) {
          float cv = dot / fmaxf(sqrtf(na) * sqrtf(nb), 1e-8f);
          out[(size_t)site * (kT * kE) + t * kE + e] = cv;
        }
      }
      LDS_FENCE();   // drain bufK reads before next iteration overwrites
    }

    #pragma unroll
    for (int j = 0; j < 16; ++j) hcur[j] = hnxt[j];
    pcur[0] = pnxt[0]; pcur[1] = pnxt[1]; pcur[2] = pnxt[2];
    site = nsite;
  }
}

}  // namespace

extern "C" void kernel_launch(void* const* d_in, const int* in_sizes, int n_in,
                              void* d_out, int out_size, void* d_ws, size_t ws_size,
                              hipStream_t stream) {
  const float* input = (const float*)d_in[0];
  const float* h0    = (const float*)d_in[1];
  const float* h1    = (const float*)d_in[2];
  const float* h2    = (const float*)d_in[3];
  const float* memw  = (const float*)d_in[4];
  const float* iq    = (const float*)d_in[5];
  const float* hq    = (const float*)d_in[6];
  const float* kw    = (const float*)d_in[7];
  const float* vw    = (const float*)d_in[8];
  float* out = (float*)d_out;

  testam_mfma<<<kE * kNB, kThreads, 0, stream>>>(
      input, h0, h1, h2, memw, iq, hq, kw, vw, out);
}

// Round 5
// 178.235 us; speedup vs baseline: 2.1954x; 1.2213x over previous
//
#include <hip/hip_runtime.h>
#include <math.h>

typedef __attribute__((ext_vector_type(8))) short short8;
typedef __attribute__((ext_vector_type(4))) float f32x4;

namespace {

constexpr int kT = 12, kMS = 20, kE = 3;
constexpr int kSites = 64 * 325;                 // 20800
constexpr int kWaves = 8;
constexpr int kThreads = kWaves * 64;            // 512
constexpr int kNB = 170;                         // blocks per expert (510 total, 2/CU)
constexpr int kStride = kNB * kWaves;            // 1360 sites per sweep
constexpr int kIters = (kSites + kStride - 1) / kStride;  // 16

// split x into hi (truncated bf16) and lo (bf16 of remainder): x ~= hi + lo
__device__ __forceinline__ void split1(float x, unsigned& hi, unsigned& lo) {
  unsigned u = __float_as_uint(x);
  hi = u >> 16;
  float r = x - __uint_as_float(u & 0xFFFF0000u);   // exact (Sterbenz)
  lo = __float_as_uint(r) >> 16;
}

__device__ __forceinline__ unsigned short bf_rtn(float x) {  // round-nearest-even bf16
  unsigned u = __float_as_uint(x);
  return (unsigned short)((u + 0x7FFFu + ((u >> 16) & 1u)) >> 16);
}

#define MFMA32(a, b, c) __builtin_amdgcn_mfma_f32_16x16x32_bf16((a), (b), (c), 0, 0, 0)
#define LDS_FENCE() asm volatile("s_waitcnt lgkmcnt(0)" ::: "memory")

// Fragment conventions (16x16x32 bf16):
//   A: lane l holds A[row = l&15][k = (l>>4)*8 + j]
//   B: lane l holds B[k = (l>>4)*8 + j][col = l&15]
//   C/D: lane l holds D[row = (l>>4)*4 + reg][col = l&15]   (m89-verified)
__global__ __launch_bounds__(kThreads, 2) void testam_mfma(
    const float* __restrict__ input, const float* __restrict__ h0,
    const float* __restrict__ h1, const float* __restrict__ h2,
    const float* __restrict__ memw, const float* __restrict__ iq,
    const float* __restrict__ hq, const float* __restrict__ kwt,
    const float* __restrict__ vw, float* __restrict__ out) {

  __shared__ __align__(16) unsigned short wlds[2][12][512];  // weight frags (hi/lo) 24KB
  __shared__ __align__(16) unsigned short mwT[2][2][512];    // scores-B: memw^T frags 4KB
  __shared__ __align__(16) unsigned short mwB[2][2][512];    // memories-B: memw frags 4KB
  __shared__ __align__(16) unsigned bufQ[kWaves][16 * 33];   // Q split-packed; later attn planes
  __shared__ __align__(16) unsigned bufK[kWaves][16 * 33];   // K split-packed; later mem-attnw
  __shared__ __align__(16) unsigned short vT[kWaves][32 * 16];  // V^T single bf16

  const int tid = threadIdx.x;
  const int e = blockIdx.x / kNB;
  const int b = blockIdx.x % kNB;
  const int l = tid & 63, wv = tid >> 6;
  const int g = l >> 4, c = l & 15;

  // ---- one-time staging: expert-e weight fragments (hi/lo) ----
  for (int idx = tid; idx < 768; idx += kThreads) {
    int ll = idx & 63, fi = idx >> 6;
    int mat = fi >> 2, k0i = (fi >> 1) & 1, n0i = fi & 1;
    int gg = ll >> 4, cc = ll & 15;
    const float* wp = ((mat == 0) ? hq : (mat == 1) ? kwt : vw) + e * 2048
                      + (k0i * 32 + gg * 8) * 32 + n0i * 16 + cc;
    short8 sh, sl;
    #pragma unroll
    for (int j = 0; j < 8; ++j) {
      unsigned h, lo; split1(wp[j * 32], h, lo);
      sh[j] = (short)h; sl[j] = (short)lo;
    }
    *(short8*)&wlds[0][fi][ll * 8] = sh;
    *(short8*)&wlds[1][fi][ll * 8] = sl;
  }
  for (int idx = tid; idx < 128; idx += kThreads) {  // B[k=m][col=s] = memw[s][m]
    int ll = idx & 63, n0i = idx >> 6;
    int gg = ll >> 4, cc = ll & 15, s = n0i * 16 + cc;
    short8 sh, sl;
    #pragma unroll
    for (int j = 0; j < 8; ++j) {
      float v = (s < kMS) ? memw[s * 32 + gg * 8 + j] : 0.f;
      unsigned h, lo; split1(v, h, lo);
      sh[j] = (short)h; sl[j] = (short)lo;
    }
    *(short8*)&mwT[0][n0i][ll * 8] = sh;
    *(short8*)&mwT[1][n0i][ll * 8] = sl;
  }
  for (int idx = tid; idx < 128; idx += kThreads) {  // B[k=s][col=m] = memw[s][m]
    int ll = idx & 63, n0i = idx >> 6;
    int gg = ll >> 4, cc = ll & 15;
    short8 sh, sl;
    #pragma unroll
    for (int j = 0; j < 8; ++j) {
      int k = gg * 8 + j;
      float v = (k < kMS) ? memw[k * 32 + n0i * 16 + cc] : 0.f;
      unsigned h, lo; split1(v, h, lo);
      sh[j] = (short)h; sl[j] = (short)lo;
    }
    *(short8*)&mwB[0][n0i][ll * 8] = sh;
    *(short8*)&mwB[1][n0i][ll * 8] = sl;
  }
  __syncthreads();

  const float* hbase = (e == 0) ? h0 : (e == 1) ? h1 : h2;

  // hoist input_query columns for this lane's m-range into registers
  float iqr0[8], iqr1[8], iqr2[8];
  #pragma unroll
  for (int j = 0; j < 8; ++j) {
    int m = g * 8 + j;
    iqr0[j] = iq[m]; iqr1[j] = iq[32 + m]; iqr2[j] = iq[64 + m];
  }

  const f32x4 fz = {0.f, 0.f, 0.f, 0.f};

  float hcur[16], hnxt[16];
  float pcur[3], pnxt[3];

  auto load_site = [&](int s, float* hr, float* pr) {
    if (s < kSites && c < kT) {
      const float* p = hbase + (size_t)s * 768 + c * 64 + g * 8;
      #pragma unroll
      for (int k0i = 0; k0i < 2; ++k0i)
        #pragma unroll
        for (int j = 0; j < 8; ++j) hr[k0i * 8 + j] = p[k0i * 32 + j];
      const float* ip = input + (size_t)s * 36 + c * 3;
      pr[0] = ip[0]; pr[1] = ip[1]; pr[2] = ip[2];
    } else {
      #pragma unroll
      for (int j = 0; j < 16; ++j) hr[j] = 0.f;
      pr[0] = pr[1] = pr[2] = 0.f;
    }
  };

  int site = b * kWaves + wv;
  load_site(site, hcur, pcur);

  for (int it = 0; it < kIters; ++it) {
    const int nsite = site + kStride;
    load_site(nsite, hnxt, pnxt);   // issue loads; consumed after body

    if (site < kSites) {
      // ---- A-fragments of h ----
      short8 ah[2], al[2];
      #pragma unroll
      for (int k0i = 0; k0i < 2; ++k0i) {
        short8 sh, sl;
        #pragma unroll
        for (int j = 0; j < 8; ++j) {
          unsigned h, lo; split1(hcur[k0i * 8 + j], h, lo);
          sh[j] = (short)h; sl[j] = (short)lo;
        }
        ah[k0i] = sh; al[k0i] = sl;
      }

      // ---- Q,K,V projections (3-term bf16x3) ----
      __builtin_amdgcn_s_setprio(1);
      #pragma unroll
      for (int mat = 0; mat < 3; ++mat) {
        f32x4 acc[2] = {fz, fz};
        #pragma unroll
        for (int n0i = 0; n0i < 2; ++n0i) {
          #pragma unroll
          for (int k0i = 0; k0i < 2; ++k0i) {
            int fi = mat * 4 + k0i * 2 + n0i;
            short8 bh = *(const short8*)&wlds[0][fi][l * 8];
            short8 bl = *(const short8*)&wlds[1][fi][l * 8];
            acc[n0i] = MFMA32(ah[k0i], bh, acc[n0i]);
            acc[n0i] = MFMA32(ah[k0i], bl, acc[n0i]);
            acc[n0i] = MFMA32(al[k0i], bh, acc[n0i]);
          }
        }
        if (mat < 2) {
          unsigned* dst = (mat == 0) ? bufQ[wv] : bufK[wv];
          #pragma unroll
          for (int n0i = 0; n0i < 2; ++n0i)
            #pragma unroll
            for (int r = 0; r < 4; ++r) {
              unsigned h, lo; split1(acc[n0i][r], h, lo);
              dst[(g * 4 + r) * 33 + n0i * 16 + c] = h | (lo << 16);
            }
        } else {
          #pragma unroll
          for (int n0i = 0; n0i < 2; ++n0i)
            #pragma unroll
            for (int r = 0; r < 4; ++r)
              vT[wv][(n0i * 16 + c) * 16 + g * 4 + r] = bf_rtn(acc[n0i][r]);
        }
      }
      __builtin_amdgcn_s_setprio(0);

      // ---- memory path (independent): q = input@iq, scores MFMAs ----
      // executes under the Q/K LDS write->read round-trip latency
      short8 qmh, qml;
      #pragma unroll
      for (int j = 0; j < 8; ++j) {
        float qv = pcur[0] * iqr0[j] + pcur[1] * iqr1[j] + pcur[2] * iqr2[j];
        unsigned h, lo; split1(qv, h, lo);
        qmh[j] = (short)h; qml[j] = (short)lo;
      }
      f32x4 sc[2];
      #pragma unroll
      for (int n0i = 0; n0i < 2; ++n0i) {
        short8 bh = *(const short8*)&mwT[0][n0i][l * 8];
        short8 bl = *(const short8*)&mwT[1][n0i][l * 8];
        sc[n0i] = MFMA32(qmh, bh, fz);
        sc[n0i] = MFMA32(qmh, bl, sc[n0i]);
        sc[n0i] = MFMA32(qml, bh, sc[n0i]);
      }

      LDS_FENCE();  // F1: Q/K/V writes visible; mwT reads drained

      // ---- energy = Q K^T ----
      short8 qh, ql, kh, kl;
      #pragma unroll
      for (int j = 0; j < 8; ++j) {
        unsigned uq = bufQ[wv][c * 33 + g * 8 + j];
        unsigned uk = bufK[wv][c * 33 + g * 8 + j];
        qh[j] = (short)(uq & 0xFFFFu); ql[j] = (short)(uq >> 16);
        kh[j] = (short)(uk & 0xFFFFu); kl[j] = (short)(uk >> 16);
      }
      f32x4 eng = fz;
      eng = MFMA32(qh, kh, eng);
      eng = MFMA32(qh, kl, eng);
      eng = MFMA32(ql, kh, eng);

      // ---- mem softmax (independent of energy result; fills MFMA latency) ----
      float w0[4], w1[4];
      #pragma unroll
      for (int r = 0; r < 4; ++r) {
        float v0 = sc[0][r];
        float v1 = (c < 4) ? sc[1][r] : -1e30f;
        float mx = fmaxf(v0, v1);
        #pragma unroll
        for (int m = 1; m < 16; m <<= 1) mx = fmaxf(mx, __shfl_xor(mx, m));
        float e0 = __expf(v0 - mx);
        float e1 = (c < 4) ? __expf(sc[1][r] - mx) : 0.f;
        float sm = e0 + e1;
        #pragma unroll
        for (int m = 1; m < 16; m <<= 1) sm += __shfl_xor(sm, m);
        float inv = 1.f / sm;
        w0[r] = e0 * inv; w1[r] = e1 * inv;
      }
      // attn-w -> bufK (K reads already issued; same-wave DS ops are in-order)
      #pragma unroll
      for (int r = 0; r < 4; ++r) {
        int t = g * 4 + r;
        unsigned h, lo; split1(w0[r], h, lo);
        bufK[wv][t * 33 + c] = h | (lo << 16);
        unsigned pv = 0u;
        if (c < 4) { split1(w1[r], h, lo); pv = h | (lo << 16); }
        bufK[wv][t * 33 + 16 + c] = pv;
      }

      // ---- QK softmax over s; attn hi/lo planes into bufQ ----
      unsigned short* attnHi = (unsigned short*)&bufQ[wv][0];
      unsigned short* attnLo = attnHi + 256;
      #pragma unroll
      for (int r = 0; r < 4; ++r) {
        float v = (c < kT) ? eng[r] : -1e30f;
        float mx = v;
        #pragma unroll
        for (int m = 1; m < 16; m <<= 1) mx = fmaxf(mx, __shfl_xor(mx, m));
        float ev = (c < kT) ? __expf(eng[r] - mx) : 0.f;
        float sm = ev;
        #pragma unroll
        for (int m = 1; m < 16; m <<= 1) sm += __shfl_xor(sm, m);
        float wgt = ev / sm;
        unsigned h, lo; split1(wgt, h, lo);
        attnHi[(g * 4 + r) * 16 + c] = (unsigned short)h;
        attnLo[(g * 4 + r) * 16 + c] = (unsigned short)lo;
      }

      LDS_FENCE();  // F2: attn planes + attn-w visible

      // ---- hidden_att = attn @ V ----
      short8 ah2, al2;
      if (g < 2) {
        ah2 = *(const short8*)&attnHi[c * 16 + g * 8];
        al2 = *(const short8*)&attnLo[c * 16 + g * 8];
      } else {
        #pragma unroll
        for (int j = 0; j < 8; ++j) { ah2[j] = 0; al2[j] = 0; }
      }
      f32x4 ha[2];
      #pragma unroll
      for (int n0i = 0; n0i < 2; ++n0i) {
        short8 bv = *(const short8*)&vT[wv][(n0i * 16 + c) * 16 + (g & 1) * 8];
        ha[n0i] = MFMA32(ah2, bv, fz);
        ha[n0i] = MFMA32(al2, bv, ha[n0i]);
      }

      // ---- memories = attnw @ memw ----
      short8 awh, awl;
      #pragma unroll
      for (int j = 0; j < 8; ++j) {
        unsigned u = bufK[wv][c * 33 + g * 8 + j];
        awh[j] = (short)(u & 0xFFFFu); awl[j] = (short)(u >> 16);
      }
      f32x4 mem[2];
      #pragma unroll
      for (int n0i = 0; n0i < 2; ++n0i) {
        short8 bh = *(const short8*)&mwB[0][n0i][l * 8];
        short8 bl = *(const short8*)&mwB[1][n0i][l * 8];
        mem[n0i] = MFMA32(awh, bh, fz);
        mem[n0i] = MFMA32(awh, bl, mem[n0i]);
        mem[n0i] = MFMA32(awl, bh, mem[n0i]);
      }

      // ---- cosine similarity + store ----
      #pragma unroll
      for (int r = 0; r < 4; ++r) {
        float dot = mem[0][r] * ha[0][r] + mem[1][r] * ha[1][r];
        float na  = mem[0][r] * mem[0][r] + mem[1][r] * mem[1][r];
        float nb  = ha[0][r] * ha[0][r] + ha[1][r] * ha[1][r];
        #pragma unroll
        for (int m = 1; m < 16; m <<= 1) {
          dot += __shfl_xor(dot, m);
          na  += __shfl_xor(na, m);
          nb  += __shfl_xor(nb, m);
        }
        int t = g * 4 + r;
        if (c == 0 && t < kT) {
          float cv = dot / fmaxf(sqrtf(na) * sqrtf(nb), 1e-8f);
          out[(size_t)site * (kT * kE) + t * kE + e] = cv;
        }
      }
      LDS_FENCE();   // drain before next iteration overwrites scratch
    }

    #pragma unroll
    for (int j = 0; j < 16; ++j) hcur[j] = hnxt[j];
    pcur[0] = pnxt[0]; pcur[1] = pnxt[1]; pcur[2] = pnxt[2];
    site = nsite;
  }
}

}  // namespace

extern "C" void kernel_launch(void* const* d_in, const int* in_sizes, int n_in,
                              void* d_out, int out_size, void* d_ws, size_t ws_size,
                              hipStream_t stream) {
  const float* input = (const float*)d_in[0];
  const float* h0    = (const float*)d_in[1];
  const float* h1    = (const float*)d_in[2];
  const float* h2    = (const float*)d_in[3];
  const float* memw  = (const float*)d_in[4];
  const float* iq    = (const float*)d_in[5];
  const float* hq    = (const float*)d_in[6];
  const float* kw    = (const float*)d_in[7];
  const float* vw    = (const float*)d_in[8];
  float* out = (float*)d_out;

  testam_mfma<<<kE * kNB, kThreads, 0, stream>>>(
      input, h0, h1, h2, memw, iq, hq, kw, vw, out);
}

// Round 6
// 103.986 us; speedup vs baseline: 3.7630x; 1.7140x over previous
//
#include <hip/hip_runtime.h>
#include <math.h>

typedef __attribute__((ext_vector_type(8))) short short8;
typedef __attribute__((ext_vector_type(4))) float f32x4;

namespace {

constexpr int kT = 12, kMS = 20, kE = 3;
constexpr int kSites = 64 * 325;                 // 20800
constexpr int kWaves = 8;
constexpr int kThreads = kWaves * 64;            // 512
constexpr int kNB = 170;                         // blocks per expert
constexpr int kStride = kNB * kWaves;            // 1360
constexpr int kIters = (kSites + kStride - 1) / kStride;  // 16

// split x into hi (truncated bf16) and lo (bf16 of remainder): x ~= hi + lo
__device__ __forceinline__ void split1(float x, unsigned& hi, unsigned& lo) {
  unsigned u = __float_as_uint(x);
  hi = u >> 16;
  float r = x - __uint_as_float(u & 0xFFFF0000u);   // exact (Sterbenz)
  lo = __float_as_uint(r) >> 16;
}
__device__ __forceinline__ unsigned short bf_rtn(float x) {
  unsigned u = __float_as_uint(x);
  return (unsigned short)((u + 0x7FFFu + ((u >> 16) & 1u)) >> 16);
}
__device__ __forceinline__ int bperm(int idx, unsigned v) {
  return __builtin_amdgcn_ds_bpermute(idx, (int)v);
}

#define MFMA32(a, b, c) __builtin_amdgcn_mfma_f32_16x16x32_bf16((a), (b), (c), 0, 0, 0)

// Fragment conventions (16x16x32 bf16), m89-verified:
//   A: lane l holds A[row = l&15][k = (l>>4)*8 + j]
//   B: lane l holds B[k = (l>>4)*8 + j][col = l&15]
//   C/D: lane l holds D[row = (l>>4)*4 + reg][col = l&15]
__global__ __launch_bounds__(kThreads, 4) void testam_mfma(
    const float* __restrict__ input, const float* __restrict__ h0,
    const float* __restrict__ h1, const float* __restrict__ h2,
    const float* __restrict__ memw, const float* __restrict__ iq,
    const float* __restrict__ hq, const float* __restrict__ kwt,
    const float* __restrict__ vw, float* __restrict__ out) {

  // Static staging only — no per-wave scratch, no fences in the body.
  __shared__ __align__(16) unsigned short wlds[2][12][512];  // Wq^T/Wk^T A-frags, Wv B-frags (24KB)
  __shared__ __align__(16) unsigned short mB[2][2][512];     // memw^T A-frags (4KB)
  __shared__ __align__(16) float Glds[32][4];                // G^T = (iq@memw^T)^T padded (512B)

  const int tid = threadIdx.x;
  const int e = blockIdx.x / kNB;
  const int b = blockIdx.x % kNB;
  const int l = tid & 63, wv = tid >> 6;
  const int g = l >> 4, c = l & 15;

  // ---- one-time staging ----
  // slots fi = mat*4 + x*2 + y: element W[y*32+8gg+j][16x+cc]
  //   Q (mat0): x=p (row-tile of Wq^T), y=k0i ; K (mat1) same ; V (mat2): x=n0i, y=k0i
  for (int idx = tid; idx < 768; idx += kThreads) {
    int ll = idx & 63, fi = idx >> 6;
    int mat = fi >> 2, x = (fi >> 1) & 1, y = fi & 1;
    int gg = ll >> 4, cc = ll & 15;
    const float* wp = ((mat == 0) ? hq : (mat == 1) ? kwt : vw) + e * 2048
                      + (y * 32 + gg * 8) * 32 + x * 16 + cc;
    short8 sh, sl;
    #pragma unroll
    for (int j = 0; j < 8; ++j) {
      unsigned h, lo; split1(wp[j * 32], h, lo);
      sh[j] = (short)h; sl[j] = (short)lo;
    }
    *(short8*)&wlds[0][fi][ll * 8] = sh;
    *(short8*)&wlds[1][fi][ll * 8] = sl;
  }
  // memw^T A-frags: frag p: lane holds memw^T[16p+cc][8gg+j] = memw[8gg+j][16p+cc]
  for (int idx = tid; idx < 128; idx += kThreads) {
    int ll = idx & 63, p = idx >> 6;
    int gg = ll >> 4, cc = ll & 15;
    short8 sh, sl;
    #pragma unroll
    for (int j = 0; j < 8; ++j) {
      int s = gg * 8 + j;
      float v = (s < kMS) ? memw[s * 32 + 16 * p + cc] : 0.f;
      unsigned h, lo; split1(v, h, lo);
      sh[j] = (short)h; sl[j] = (short)lo;
    }
    *(short8*)&mB[0][p][ll * 8] = sh;
    *(short8*)&mB[1][p][ll * 8] = sl;
  }
  // G^T[s][d] = sum_m iq[d][m]*memw[s][m]  (f32, zero-padded)
  for (int idx = tid; idx < 128; idx += kThreads) {
    int s = idx >> 2, d = idx & 3;
    float acc = 0.f;
    if (d < 3 && s < kMS) {
      for (int m = 0; m < 32; ++m) acc += iq[d * 32 + m] * memw[s * 32 + m];
    }
    Glds[s][d] = acc;
  }
  __syncthreads();

  const float* hbase = (e == 0) ? h0 : (e == 1) ? h1 : h2;
  const f32x4 fz = {0.f, 0.f, 0.f, 0.f};

  // bpermute lane indices (source lane = 16*((2g + (j>>2))&3) + c), byte units
  const int idxA = ((((2 * g) & 3) << 4) + c) << 2;      // j = 0..3
  const int idxB = ((((2 * g + 1) & 3) << 4) + c) << 2;  // j = 4..7

  float hcur[16], hnxt[16];
  float pcur[3], pnxt[3];

  auto load_site = [&](int s, float* hr, float* pr) {
    if (s < kSites && c < kT) {
      const float* p = hbase + (size_t)s * 768 + c * 64 + g * 8;
      #pragma unroll
      for (int k0i = 0; k0i < 2; ++k0i)
        #pragma unroll
        for (int j = 0; j < 8; ++j) hr[k0i * 8 + j] = p[k0i * 32 + j];
      const float* ip = input + (size_t)s * 36 + c * 3;
      pr[0] = ip[0]; pr[1] = ip[1]; pr[2] = ip[2];
    } else {
      #pragma unroll
      for (int j = 0; j < 16; ++j) hr[j] = 0.f;
      pr[0] = pr[1] = pr[2] = 0.f;
    }
  };

  int site = b * kWaves + wv;
  load_site(site, hcur, pcur);

  for (int it = 0; it < kIters; ++it) {
    const int nsite = site + kStride;
    load_site(nsite, hnxt, pnxt);

    if (site < kSites) {
      // ---- h A-frags (double as h^T B-frags) ----
      short8 ah[2], al[2];
      #pragma unroll
      for (int k0i = 0; k0i < 2; ++k0i) {
        short8 sh, sl;
        #pragma unroll
        for (int j = 0; j < 8; ++j) {
          unsigned h, lo; split1(hcur[k0i * 8 + j], h, lo);
          sh[j] = (short)h; sl[j] = (short)lo;
        }
        ah[k0i] = sh; al[k0i] = sl;
      }

      // ---- Q^T = Wq^T h^T, K^T = Wk^T h^T (swapped), V = h Wv (direct) ----
      f32x4 cq[2] = {fz, fz}, ck[2] = {fz, fz}, cv[2] = {fz, fz};
      __builtin_amdgcn_s_setprio(1);
      #pragma unroll
      for (int p = 0; p < 2; ++p) {
        #pragma unroll
        for (int k0i = 0; k0i < 2; ++k0i) {
          {  // Q: A = Wq^T frag (p,k0i), B = h^T (= ah/al)
            int fi = 0 * 4 + p * 2 + k0i;
            short8 wh = *(const short8*)&wlds[0][fi][l * 8];
            short8 wl = *(const short8*)&wlds[1][fi][l * 8];
            cq[p] = MFMA32(wh, ah[k0i], cq[p]);
            cq[p] = MFMA32(wh, al[k0i], cq[p]);
            cq[p] = MFMA32(wl, ah[k0i], cq[p]);
          }
          {  // K
            int fi = 1 * 4 + p * 2 + k0i;
            short8 wh = *(const short8*)&wlds[0][fi][l * 8];
            short8 wl = *(const short8*)&wlds[1][fi][l * 8];
            ck[p] = MFMA32(wh, ah[k0i], ck[p]);
            ck[p] = MFMA32(wh, al[k0i], ck[p]);
            ck[p] = MFMA32(wl, ah[k0i], ck[p]);
          }
          {  // V: A = h, B = Wv frag (x=n0i=p, y=k0i)
            int fi = 2 * 4 + p * 2 + k0i;
            short8 wh = *(const short8*)&wlds[0][fi][l * 8];
            short8 wl = *(const short8*)&wlds[1][fi][l * 8];
            cv[p] = MFMA32(ah[k0i], wh, cv[p]);
            cv[p] = MFMA32(ah[k0i], wl, cv[p]);
            cv[p] = MFMA32(al[k0i], wh, cv[p]);
          }
        }
      }
      __builtin_amdgcn_s_setprio(0);

      // ---- gather Q,K into energy frags: X[c][8g+j] from C-layout (p-split) ----
      unsigned qhp[4], qlp[4], khp[4], klp[4];
      #pragma unroll
      for (int r = 0; r < 4; ++r) {
        unsigned h0p, l0p, h1p, l1p;
        split1(cq[0][r], h0p, l0p); split1(cq[1][r], h1p, l1p);
        qhp[r] = h0p | (h1p << 16); qlp[r] = l0p | (l1p << 16);
        split1(ck[0][r], h0p, l0p); split1(ck[1][r], h1p, l1p);
        khp[r] = h0p | (h1p << 16); klp[r] = l0p | (l1p << 16);
      }
      short8 aqh, aql, akh, akl;
      #pragma unroll
      for (int j = 0; j < 8; ++j) {
        const int idx = (j < 4) ? idxA : idxB;
        unsigned uqh = (unsigned)bperm(idx, qhp[j & 3]);
        unsigned uql = (unsigned)bperm(idx, qlp[j & 3]);
        unsigned ukh = (unsigned)bperm(idx, khp[j & 3]);
        unsigned ukl = (unsigned)bperm(idx, klp[j & 3]);
        // p = g>>1: lanes g<2 take lo16 (p=0), g>=2 hi16 (p=1)
        aqh[j] = (short)((g < 2) ? (uqh & 0xFFFFu) : (uqh >> 16));
        aql[j] = (short)((g < 2) ? (uql & 0xFFFFu) : (uql >> 16));
        akh[j] = (short)((g < 2) ? (ukh & 0xFFFFu) : (ukh >> 16));
        akl[j] = (short)((g < 2) ? (ukl & 0xFFFFu) : (ukl >> 16));
      }

      // ---- energy^T = K Q^T (3-term) ----
      f32x4 eng = fz;
      eng = MFMA32(akh, aqh, eng);
      eng = MFMA32(akh, aql, eng);
      eng = MFMA32(akl, aqh, eng);
      // lane holds energy^T[s = 4g+r][t = c]

      // ---- softmax over s (rows): per-lane 4 regs + xor16/32 shuffles ----
      float w[4];
      {
        float mloc = -1e30f;
        if (g < 3) {
          mloc = eng[0];
          #pragma unroll
          for (int r = 1; r < 4; ++r) mloc = fmaxf(mloc, eng[r]);
        }
        float mx = mloc;
        mx = fmaxf(mx, __shfl_xor(mx, 16));
        mx = fmaxf(mx, __shfl_xor(mx, 32));
        float sloc = 0.f;
        #pragma unroll
        for (int r = 0; r < 4; ++r) {
          w[r] = (g < 3) ? __expf(eng[r] - mx) : 0.f;
          sloc += w[r];
        }
        float sm = sloc;
        sm += __shfl_xor(sm, 16);
        sm += __shfl_xor(sm, 32);
        float inv = 1.f / sm;
        #pragma unroll
        for (int r = 0; r < 4; ++r) w[r] *= inv;
      }

      // ---- attn^T gather -> B-frag attn[c][8g+j] (hi/lo), zero s>=12 ----
      unsigned wpk[4];
      #pragma unroll
      for (int r = 0; r < 4; ++r) {
        unsigned h, lo; split1(w[r], h, lo);
        wpk[r] = h | (lo << 16);
      }
      short8 bh, bl;
      #pragma unroll
      for (int j = 0; j < 8; ++j) {
        const int idx = (j < 4) ? idxA : idxB;
        unsigned u = (unsigned)bperm(idx, wpk[j & 3]);
        int s = 8 * g + j;
        bh[j] = (short)((s < kT) ? (u & 0xFFFFu) : 0u);
        bl[j] = (short)((s < kT) ? (u >> 16) : 0u);
      }

      // ---- V^T gather -> A-frags av[p][j] = V[8g+j][16p+c] (single bf16) ----
      unsigned vpk[4];
      #pragma unroll
      for (int r = 0; r < 4; ++r)
        vpk[r] = (unsigned)bf_rtn(cv[0][r]) | ((unsigned)bf_rtn(cv[1][r]) << 16);
      short8 av0, av1;
      #pragma unroll
      for (int j = 0; j < 8; ++j) {
        const int idx = (j < 4) ? idxA : idxB;
        unsigned u = (unsigned)bperm(idx, vpk[j & 3]);
        av0[j] = (short)(u & 0xFFFFu);
        av1[j] = (short)(u >> 16);
      }

      // ---- ha^T = V^T attn^T : lane holds ha[t=c][m=16p+4g+r] ----
      f32x4 hat[2];
      hat[0] = MFMA32(av0, bh, fz);  hat[0] = MFMA32(av0, bl, hat[0]);
      hat[1] = MFMA32(av1, bh, fz);  hat[1] = MFMA32(av1, bl, hat[1]);

      // ---- mem scores^T[s][t=c] = sum_d input[c][d] * G[d][s] (VALU) ----
      float sc0[4], sc1[4];
      #pragma unroll
      for (int r = 0; r < 4; ++r) {
        {
          const float* Gp = &Glds[4 * g + r][0];          // s = 4g+r (broadcast read)
          sc0[r] = pcur[0] * Gp[0] + pcur[1] * Gp[1] + pcur[2] * Gp[2];
        }
        {
          const float* Gp = &Glds[16 + 4 * g + r][0];     // s = 16+4g+r
          sc1[r] = pcur[0] * Gp[0] + pcur[1] * Gp[1] + pcur[2] * Gp[2];
        }
      }
      // softmax over s=0..19: p=0 rows all valid, p=1 valid only g==0
      float w0[4], w1[4];
      {
        float mloc = sc0[0];
        #pragma unroll
        for (int r = 1; r < 4; ++r) mloc = fmaxf(mloc, sc0[r]);
        if (g == 0) {
          #pragma unroll
          for (int r = 0; r < 4; ++r) mloc = fmaxf(mloc, sc1[r]);
        }
        float mx = mloc;
        mx = fmaxf(mx, __shfl_xor(mx, 16));
        mx = fmaxf(mx, __shfl_xor(mx, 32));
        float sloc = 0.f;
        #pragma unroll
        for (int r = 0; r < 4; ++r) {
          w0[r] = __expf(sc0[r] - mx); sloc += w0[r];
          w1[r] = (g == 0) ? __expf(sc1[r] - mx) : 0.f; sloc += w1[r];
        }
        float sm = sloc;
        sm += __shfl_xor(sm, 16);
        sm += __shfl_xor(sm, 32);
        float inv = 1.f / sm;
        #pragma unroll
        for (int r = 0; r < 4; ++r) { w0[r] *= inv; w1[r] *= inv; }
      }

      // ---- attnw^T gather -> B-frag attnw[c][8g+j] hi/lo (p-split, zero s>=20) ----
      unsigned hp[4], lp[4];
      #pragma unroll
      for (int r = 0; r < 4; ++r) {
        unsigned h0p, l0p, h1p, l1p;
        split1(w0[r], h0p, l0p); split1(w1[r], h1p, l1p);
        hp[r] = h0p | (h1p << 16); lp[r] = l0p | (l1p << 16);
      }
      short8 bwh, bwl;
      #pragma unroll
      for (int j = 0; j < 8; ++j) {
        const int idx = (j < 4) ? idxA : idxB;
        unsigned uh = (unsigned)bperm(idx, hp[j & 3]);
        unsigned ul = (unsigned)bperm(idx, lp[j & 3]);
        int s = 8 * g + j;
        unsigned vh = (g < 2) ? (uh & 0xFFFFu) : (uh >> 16);
        unsigned vl = (g < 2) ? (ul & 0xFFFFu) : (ul >> 16);
        bwh[j] = (short)((s < kMS) ? vh : 0u);
        bwl[j] = (short)((s < kMS) ? vl : 0u);
      }

      // ---- memories^T = memw^T attnw^T (3-term): lane holds mem[t=c][m=16p+4g+r] ----
      f32x4 cmem[2];
      #pragma unroll
      for (int p = 0; p < 2; ++p) {
        short8 mh = *(const short8*)&mB[0][p][l * 8];
        short8 ml = *(const short8*)&mB[1][p][l * 8];
        cmem[p] = MFMA32(mh, bwh, fz);
        cmem[p] = MFMA32(mh, bwl, cmem[p]);
        cmem[p] = MFMA32(ml, bwh, cmem[p]);
      }

      // ---- cosine similarity over m (regs + xor16/32), store at g==0 ----
      float dot = 0.f, na = 0.f, nb = 0.f;
      #pragma unroll
      for (int p = 0; p < 2; ++p)
        #pragma unroll
        for (int r = 0; r < 4; ++r) {
          float a = cmem[p][r], h = hat[p][r];
          dot += a * h; na += a * a; nb += h * h;
        }
      dot += __shfl_xor(dot, 16); dot += __shfl_xor(dot, 32);
      na  += __shfl_xor(na, 16);  na  += __shfl_xor(na, 32);
      nb  += __shfl_xor(nb, 16);  nb  += __shfl_xor(nb, 32);
      if (g == 0 && c < kT) {
        float cvv = dot / fmaxf(sqrtf(na) * sqrtf(nb), 1e-8f);
        out[(size_t)site * (kT * kE) + c * kE + e] = cvv;
      }
    }

    #pragma unroll
    for (int j = 0; j < 16; ++j) hcur[j] = hnxt[j];
    pcur[0] = pnxt[0]; pcur[1] = pnxt[1]; pcur[2] = pnxt[2];
    site = nsite;
  }
}

}  // namespace

extern "C" void kernel_launch(void* const* d_in, const int* in_sizes, int n_in,
                              void* d_out, int out_size, void* d_ws, size_t ws_size,
                              hipStream_t stream) {
  const float* input = (const float*)d_in[0];
  const float* h0    = (const float*)d_in[1];
  const float* h1    = (const float*)d_in[2];
  const float* h2    = (const float*)d_in[3];
  const float* memw  = (const float*)d_in[4];
  const float* iq    = (const float*)d_in[5];
  const float* hq    = (const float*)d_in[6];
  const float* kw    = (const float*)d_in[7];
  const float* vw    = (const float*)d_in[8];
  float* out = (float*)d_out;

  testam_mfma<<<kE * kNB, kThreads, 0, stream>>>(
      input, h0, h1, h2, memw, iq, hq, kw, vw, out);
}

// Round 7
// 96.425 us; speedup vs baseline: 4.0581x; 1.0784x over previous
//
#include <hip/hip_runtime.h>
#include <math.h>

typedef __attribute__((ext_vector_type(8))) short short8;
typedef __attribute__((ext_vector_type(4))) float f32x4;

namespace {

constexpr int kT = 12, kMS = 20, kE = 3;
constexpr int kSites = 64 * 325;                 // 20800
constexpr int kWaves = 8;
constexpr int kThreads = kWaves * 64;            // 512
constexpr int kNB = 340;                         // blocks per expert (1020 total ~ 4/CU)
constexpr int kStride = kNB * kWaves;            // 2720
constexpr int kIters = (kSites + kStride - 1) / kStride;  // 8

// split x into hi (truncated bf16) and lo (bf16 of remainder): x ~= hi + lo
__device__ __forceinline__ void split1(float x, unsigned& hi, unsigned& lo) {
  unsigned u = __float_as_uint(x);
  hi = u >> 16;
  float r = x - __uint_as_float(u & 0xFFFF0000u);   // exact (Sterbenz)
  lo = __float_as_uint(r) >> 16;
}
__device__ __forceinline__ float btrunc(float x) {
  return __uint_as_float(__float_as_uint(x) & 0xFFFF0000u);
}
// pack {bf_trunc(b) : bf_trunc(a)} (a in low16) — one v_perm_b32
__device__ __forceinline__ unsigned pk_hi(float a, float b) {
  return __builtin_amdgcn_perm(__float_as_uint(b), __float_as_uint(a), 0x07060302u);
}
// pack with round-half-up (error class of RNE, 2^-9 rel)
__device__ __forceinline__ unsigned pk_rnd(float a, float b) {
  return __builtin_amdgcn_perm(__float_as_uint(b) + 0x8000u,
                               __float_as_uint(a) + 0x8000u, 0x07060302u);
}
__device__ __forceinline__ unsigned perm(unsigned hi_src, unsigned lo_src, unsigned sel) {
  return __builtin_amdgcn_perm(hi_src, lo_src, sel);
}
__device__ __forceinline__ int bperm(int idx, unsigned v) {
  return __builtin_amdgcn_ds_bpermute(idx, (int)v);
}

union S8 { short8 s; unsigned u[4]; };

#define MFMA32(a, b, c) __builtin_amdgcn_mfma_f32_16x16x32_bf16((a), (b), (c), 0, 0, 0)

constexpr unsigned kSelLo = 0x05040100u;  // take low16 of each source
constexpr unsigned kSelHi = 0x07060302u;  // take high16 of each source

// Fragment conventions (16x16x32 bf16), m89-verified:
//   A: lane l holds A[row = l&15][k = (l>>4)*8 + j]
//   B: lane l holds B[k = (l>>4)*8 + j][col = l&15]
//   C/D: lane l holds D[row = (l>>4)*4 + reg][col = l&15]
__global__ __launch_bounds__(kThreads, 4) void testam_mfma(
    const float* __restrict__ input, const float* __restrict__ h0,
    const float* __restrict__ h1, const float* __restrict__ h2,
    const float* __restrict__ memw, const float* __restrict__ iq,
    const float* __restrict__ hq, const float* __restrict__ kwt,
    const float* __restrict__ vw, float* __restrict__ out) {

  __shared__ __align__(16) unsigned short wlds[2][12][512];  // Wq^T/Wk^T A-frags, Wv B-frags
  __shared__ __align__(16) unsigned short mB[2][2][512];     // memw^T A-frags
  __shared__ __align__(16) float Glds[32][4];                // G^T = (iq@memw^T)^T padded

  const int tid = threadIdx.x;
  const int e = blockIdx.x / kNB;
  const int b = blockIdx.x % kNB;
  const int l = tid & 63, wv = tid >> 6;
  const int g = l >> 4, c = l & 15;

  // ---- one-time staging ----
  for (int idx = tid; idx < 768; idx += kThreads) {
    int ll = idx & 63, fi = idx >> 6;
    int mat = fi >> 2, x = (fi >> 1) & 1, y = fi & 1;
    int gg = ll >> 4, cc = ll & 15;
    const float* wp = ((mat == 0) ? hq : (mat == 1) ? kwt : vw) + e * 2048
                      + (y * 32 + gg * 8) * 32 + x * 16 + cc;
    short8 sh, sl;
    #pragma unroll
    for (int j = 0; j < 8; ++j) {
      unsigned h, lo; split1(wp[j * 32], h, lo);
      sh[j] = (short)h; sl[j] = (short)lo;
    }
    *(short8*)&wlds[0][fi][ll * 8] = sh;
    *(short8*)&wlds[1][fi][ll * 8] = sl;
  }
  for (int idx = tid; idx < 128; idx += kThreads) {
    int ll = idx & 63, p = idx >> 6;
    int gg = ll >> 4, cc = ll & 15;
    short8 sh, sl;
    #pragma unroll
    for (int j = 0; j < 8; ++j) {
      int s = gg * 8 + j;
      float v = (s < kMS) ? memw[s * 32 + 16 * p + cc] : 0.f;
      unsigned h, lo; split1(v, h, lo);
      sh[j] = (short)h; sl[j] = (short)lo;
    }
    *(short8*)&mB[0][p][ll * 8] = sh;
    *(short8*)&mB[1][p][ll * 8] = sl;
  }
  for (int idx = tid; idx < 128; idx += kThreads) {
    int s = idx >> 2, d = idx & 3;
    float acc = 0.f;
    if (d < 3 && s < kMS) {
      for (int m = 0; m < 32; ++m) acc += iq[d * 32 + m] * memw[s * 32 + m];
    }
    Glds[s][d] = acc;
  }
  __syncthreads();

  const float* hbase = (e == 0) ? h0 : (e == 1) ? h1 : h2;
  const f32x4 fz = {0.f, 0.f, 0.f, 0.f};

  // bpermute lane indices (byte units); pairs never straddle the j=4 boundary
  const int idxA = ((((2 * g) & 3) << 4) + c) << 2;      // j = 0..3
  const int idxB = ((((2 * g + 1) & 3) << 4) + c) << 2;  // j = 4..7
  // p-half selector: lanes g<2 take p=0 (low16), g>=2 take p=1 (high16)
  const unsigned selH = (g < 2) ? kSelLo : kSelHi;
  // pair-uniform validity masks (k = 8g + j)
  const unsigned mT01 = (g < 2) ? 0xFFFFFFFFu : 0u;  // attn  pairs jj=0,1: k<12
  const unsigned mT23 = (g == 0) ? 0xFFFFFFFFu : 0u; // attn  pairs jj=2,3
  const unsigned mW01 = (g < 3) ? 0xFFFFFFFFu : 0u;  // attnw pairs jj=0,1: k<20
  const unsigned mW23 = (g < 2) ? 0xFFFFFFFFu : 0u;  // attnw pairs jj=2,3

  float hcur[16], hnxt[16];
  float pcur[3], pnxt[3];

  auto load_site = [&](int s, float* hr, float* pr) {
    if (s < kSites && c < kT) {
      const float* p = hbase + (size_t)s * 768 + c * 64 + g * 8;
      #pragma unroll
      for (int k0i = 0; k0i < 2; ++k0i)
        #pragma unroll
        for (int j = 0; j < 8; ++j) hr[k0i * 8 + j] = p[k0i * 32 + j];
      const float* ip = input + (size_t)s * 36 + c * 3;
      pr[0] = ip[0]; pr[1] = ip[1]; pr[2] = ip[2];
    } else {
      #pragma unroll
      for (int j = 0; j < 16; ++j) hr[j] = 0.f;
      pr[0] = pr[1] = pr[2] = 0.f;
    }
  };

  int site = b * kWaves + wv;
  load_site(site, hcur, pcur);

  for (int it = 0; it < kIters; ++it) {
    const int nsite = site + kStride;
    load_site(nsite, hnxt, pnxt);

    if (site < kSites) {
      // ---- h A-frags (double as h^T B-frags): u32-wise build ----
      S8 ah[2], al[2];
      #pragma unroll
      for (int k0i = 0; k0i < 2; ++k0i) {
        #pragma unroll
        for (int jj = 0; jj < 4; ++jj) {
          float a = hcur[k0i * 8 + 2 * jj], bb = hcur[k0i * 8 + 2 * jj + 1];
          ah[k0i].u[jj] = pk_hi(a, bb);
          al[k0i].u[jj] = pk_hi(a - btrunc(a), bb - btrunc(bb));
        }
      }

      // ---- Q^T = Wq^T h^T, K^T = Wk^T h^T (swapped), V = h Wv ----
      f32x4 cq[2] = {fz, fz}, ck[2] = {fz, fz}, cv[2] = {fz, fz};
      __builtin_amdgcn_s_setprio(1);
      #pragma unroll
      for (int p = 0; p < 2; ++p) {
        #pragma unroll
        for (int k0i = 0; k0i < 2; ++k0i) {
          {
            int fi = 0 * 4 + p * 2 + k0i;
            short8 wh = *(const short8*)&wlds[0][fi][l * 8];
            short8 wl = *(const short8*)&wlds[1][fi][l * 8];
            cq[p] = MFMA32(wh, ah[k0i].s, cq[p]);
            cq[p] = MFMA32(wh, al[k0i].s, cq[p]);
            cq[p] = MFMA32(wl, ah[k0i].s, cq[p]);
          }
          {
            int fi = 1 * 4 + p * 2 + k0i;
            short8 wh = *(const short8*)&wlds[0][fi][l * 8];
            short8 wl = *(const short8*)&wlds[1][fi][l * 8];
            ck[p] = MFMA32(wh, ah[k0i].s, ck[p]);
            ck[p] = MFMA32(wh, al[k0i].s, ck[p]);
            ck[p] = MFMA32(wl, ah[k0i].s, ck[p]);
          }
          {
            int fi = 2 * 4 + p * 2 + k0i;
            short8 wh = *(const short8*)&wlds[0][fi][l * 8];
            short8 wl = *(const short8*)&wlds[1][fi][l * 8];
            cv[p] = MFMA32(ah[k0i].s, wh, cv[p]);
            cv[p] = MFMA32(ah[k0i].s, wl, cv[p]);
            cv[p] = MFMA32(al[k0i].s, wh, cv[p]);
          }
        }
      }
      __builtin_amdgcn_s_setprio(0);

      // ---- Q,K p-packed planes (hi/lo) ----
      unsigned qhp[4], qlp[4], khp[4], klp[4];
      #pragma unroll
      for (int r = 0; r < 4; ++r) {
        float a = cq[0][r], bb = cq[1][r];
        qhp[r] = pk_hi(a, bb);
        qlp[r] = pk_hi(a - btrunc(a), bb - btrunc(bb));
        a = ck[0][r]; bb = ck[1][r];
        khp[r] = pk_hi(a, bb);
        klp[r] = pk_hi(a - btrunc(a), bb - btrunc(bb));
      }
      // gather -> energy frags (pairwise: 2 bperm + 1 perm per u32 word)
      S8 aqh, aql, akh, akl;
      #pragma unroll
      for (int jj = 0; jj < 4; ++jj) {
        const int idx = (jj < 2) ? idxA : idxB;
        const int r0 = (2 * jj) & 3, r1 = (2 * jj + 1) & 3;
        aqh.u[jj] = perm((unsigned)bperm(idx, qhp[r1]), (unsigned)bperm(idx, qhp[r0]), selH);
        aql.u[jj] = perm((unsigned)bperm(idx, qlp[r1]), (unsigned)bperm(idx, qlp[r0]), selH);
        akh.u[jj] = perm((unsigned)bperm(idx, khp[r1]), (unsigned)bperm(idx, khp[r0]), selH);
        akl.u[jj] = perm((unsigned)bperm(idx, klp[r1]), (unsigned)bperm(idx, klp[r0]), selH);
      }

      // ---- energy^T = K Q^T (3-term) ----
      f32x4 eng = fz;
      eng = MFMA32(akh.s, aqh.s, eng);
      eng = MFMA32(akh.s, aql.s, eng);
      eng = MFMA32(akl.s, aqh.s, eng);
      // lane holds energy^T[s = 4g+r][t = c]

      // ---- softmax over s (rows) ----
      float w[4];
      {
        float mloc = -1e30f;
        if (g < 3) {
          mloc = eng[0];
          #pragma unroll
          for (int r = 1; r < 4; ++r) mloc = fmaxf(mloc, eng[r]);
        }
        float mx = mloc;
        mx = fmaxf(mx, __shfl_xor(mx, 16));
        mx = fmaxf(mx, __shfl_xor(mx, 32));
        float sloc = 0.f;
        #pragma unroll
        for (int r = 0; r < 4; ++r) {
          w[r] = (g < 3) ? __expf(eng[r] - mx) : 0.f;
          sloc += w[r];
        }
        float sm = sloc;
        sm += __shfl_xor(sm, 16);
        sm += __shfl_xor(sm, 32);
        float inv = 1.f / sm;
        #pragma unroll
        for (int r = 0; r < 4; ++r) w[r] *= inv;
      }

      // ---- attn^T gather -> B-frag (hi|lo packed per value) ----
      unsigned wpk[4];
      #pragma unroll
      for (int r = 0; r < 4; ++r) wpk[r] = pk_hi(w[r], w[r] - btrunc(w[r]));
      S8 bh, bl;
      #pragma unroll
      for (int jj = 0; jj < 4; ++jj) {
        const int idx = (jj < 2) ? idxA : idxB;
        const unsigned msk = (jj < 2) ? mT01 : mT23;
        unsigned u0 = (unsigned)bperm(idx, wpk[(2 * jj) & 3]);
        unsigned u1 = (unsigned)bperm(idx, wpk[(2 * jj + 1) & 3]);
        bh.u[jj] = perm(u1, u0, kSelLo) & msk;
        bl.u[jj] = perm(u1, u0, kSelHi) & msk;
      }

      // ---- V^T gather -> A-frags (single bf16, p-split planes) ----
      unsigned vpk[4];
      #pragma unroll
      for (int r = 0; r < 4; ++r) vpk[r] = pk_rnd(cv[0][r], cv[1][r]);
      S8 av0, av1;
      #pragma unroll
      for (int jj = 0; jj < 4; ++jj) {
        const int idx = (jj < 2) ? idxA : idxB;
        unsigned u0 = (unsigned)bperm(idx, vpk[(2 * jj) & 3]);
        unsigned u1 = (unsigned)bperm(idx, vpk[(2 * jj + 1) & 3]);
        av0.u[jj] = perm(u1, u0, kSelLo);
        av1.u[jj] = perm(u1, u0, kSelHi);
      }

      // ---- ha^T = V^T attn^T : lane holds ha[t=c][m=16p+4g+r] ----
      f32x4 hat[2];
      hat[0] = MFMA32(av0.s, bh.s, fz);  hat[0] = MFMA32(av0.s, bl.s, hat[0]);
      hat[1] = MFMA32(av1.s, bh.s, fz);  hat[1] = MFMA32(av1.s, bl.s, hat[1]);

      // ---- mem scores^T[s][t=c] (VALU via precomputed G) ----
      float sc0[4], sc1[4];
      #pragma unroll
      for (int r = 0; r < 4; ++r) {
        const float* Gp = &Glds[4 * g + r][0];
        sc0[r] = pcur[0] * Gp[0] + pcur[1] * Gp[1] + pcur[2] * Gp[2];
        const float* Gq = &Glds[16 + 4 * g + r][0];
        sc1[r] = pcur[0] * Gq[0] + pcur[1] * Gq[1] + pcur[2] * Gq[2];
      }
      float w0[4], w1[4];
      {
        float mloc = sc0[0];
        #pragma unroll
        for (int r = 1; r < 4; ++r) mloc = fmaxf(mloc, sc0[r]);
        if (g == 0) {
          #pragma unroll
          for (int r = 0; r < 4; ++r) mloc = fmaxf(mloc, sc1[r]);
        }
        float mx = mloc;
        mx = fmaxf(mx, __shfl_xor(mx, 16));
        mx = fmaxf(mx, __shfl_xor(mx, 32));
        float sloc = 0.f;
        #pragma unroll
        for (int r = 0; r < 4; ++r) {
          w0[r] = __expf(sc0[r] - mx); sloc += w0[r];
          w1[r] = (g == 0) ? __expf(sc1[r] - mx) : 0.f; sloc += w1[r];
        }
        float sm = sloc;
        sm += __shfl_xor(sm, 16);
        sm += __shfl_xor(sm, 32);
        float inv = 1.f / sm;
        #pragma unroll
        for (int r = 0; r < 4; ++r) { w0[r] *= inv; w1[r] *= inv; }
      }

      // ---- attnw^T gather -> B-frag (p-split hi/lo planes) ----
      unsigned hp[4], lp[4];
      #pragma unroll
      for (int r = 0; r < 4; ++r) {
        hp[r] = pk_hi(w0[r], w1[r]);
        lp[r] = pk_hi(w0[r] - btrunc(w0[r]), w1[r] - btrunc(w1[r]));
      }
      S8 bwh, bwl;
      #pragma unroll
      for (int jj = 0; jj < 4; ++jj) {
        const int idx = (jj < 2) ? idxA : idxB;
        const unsigned msk = (jj < 2) ? mW01 : mW23;
        unsigned uh0 = (unsigned)bperm(idx, hp[(2 * jj) & 3]);
        unsigned uh1 = (unsigned)bperm(idx, hp[(2 * jj + 1) & 3]);
        unsigned ul0 = (unsigned)bperm(idx, lp[(2 * jj) & 3]);
        unsigned ul1 = (unsigned)bperm(idx, lp[(2 * jj + 1) & 3]);
        bwh.u[jj] = perm(uh1, uh0, selH) & msk;
        bwl.u[jj] = perm(ul1, ul0, selH) & msk;
      }

      // ---- memories^T = memw^T attnw^T (3-term) ----
      f32x4 cmem[2];
      #pragma unroll
      for (int p = 0; p < 2; ++p) {
        short8 mh = *(const short8*)&mB[0][p][l * 8];
        short8 ml = *(const short8*)&mB[1][p][l * 8];
        cmem[p] = MFMA32(mh, bwh.s, fz);
        cmem[p] = MFMA32(mh, bwl.s, cmem[p]);
        cmem[p] = MFMA32(ml, bwh.s, cmem[p]);
      }

      // ---- cosine similarity over m, store at g==0 ----
      float dot = 0.f, na = 0.f, nb = 0.f;
      #pragma unroll
      for (int p = 0; p < 2; ++p)
        #pragma unroll
        for (int r = 0; r < 4; ++r) {
          float a = cmem[p][r], h = hat[p][r];
          dot += a * h; na += a * a; nb += h * h;
        }
      dot += __shfl_xor(dot, 16); dot += __shfl_xor(dot, 32);
      na  += __shfl_xor(na, 16);  na  += __shfl_xor(na, 32);
      nb  += __shfl_xor(nb, 16);  nb  += __shfl_xor(nb, 32);
      if (g == 0 && c < kT) {
        float cvv = dot / fmaxf(sqrtf(na) * sqrtf(nb), 1e-8f);
        out[(size_t)site * (kT * kE) + c * kE + e] = cvv;
      }
    }

    #pragma unroll
    for (int j = 0; j < 16; ++j) hcur[j] = hnxt[j];
    pcur[0] = pnxt[0]; pcur[1] = pnxt[1]; pcur[2] = pnxt[2];
    site = nsite;
  }
}

}  // namespace

extern "C" void kernel_launch(void* const* d_in, const int* in_sizes, int n_in,
                              void* d_out, int out_size, void* d_ws, size_t ws_size,
                              hipStream_t stream) {
  const float* input = (const float*)d_in[0];
  const float* h0    = (const float*)d_in[1];
  const float* h1    = (const float*)d_in[2];
  const float* h2    = (const float*)d_in[3];
  const float* memw  = (const float*)d_in[4];
  const float* iq    = (const float*)d_in[5];
  const float* hq    = (const float*)d_in[6];
  const float* kw    = (const float*)d_in[7];
  const float* vw    = (const float*)d_in[8];
  float* out = (float*)d_out;

  testam_mfma<<<kE * kNB, kThreads, 0, stream>>>(
      input, h0, h1, h2, memw, iq, hq, kw, vw, out);
}